// Round 5
// baseline (45.838 us; speedup 1.0000x reference)
//
#include <hip/hip_runtime.h>

namespace {
constexpr int B_ = 32, S_ = 8, T_ = 128, D_ = 768, A_ = 8, L_ = 8;
constexpr int BS = B_ * S_;                 // 256
constexpr int MEAN_ELEMS = BS * D_;         // 196608
constexpr int EXT_ELEMS  = BS * A_ * D_;    // 1572864
constexpr int D4 = D_ / 4;                  // 192 float4 per row
constexpr int TSPLIT = 8, TCH = T_ / TSPLIT;      // 16 rows per partial block
constexpr int PART_BLOCKS = BS * TSPLIT;    // 2048
constexpr int EXT_BLOCKS  = BS * A_;        // 2048
constexpr int NTHR = 192;                   // one float4 column per thread
constexpr size_t WS_FLOATS = (size_t)TSPLIT * BS * D_;  // 6.29 MB

// ---- dispatch 1: mean partials (deep streaming) + extract (batched gathers) ----
__global__ void __launch_bounds__(NTHR) srl_main(
    const float* __restrict__ emb,
    const int* __restrict__ sids,
    const int* __restrict__ pred,
    const int* __restrict__ arg0,
    const int* __restrict__ arg1,
    float* __restrict__ ws,
    float* __restrict__ out)
{
    const int blk = blockIdx.x;
    const int tid = threadIdx.x;

    if (blk < PART_BLOCKS) {
        // mean partial: block (bs, ch) sums 16 rows, one float4 column/thread
        int bs = blk >> 3, ch = blk & 7;
        const float4* p = reinterpret_cast<const float4*>(emb + (size_t)bs * T_ * D_)
                          + (size_t)(ch * TCH) * D4 + tid;
        float4 acc = {0.f, 0.f, 0.f, 0.f};
        #pragma unroll   // full unroll: 16 independent loads in flight
        for (int t = 0; t < TCH; ++t) {
            float4 v = p[(size_t)t * D4];
            acc.x += v.x; acc.y += v.y; acc.z += v.z; acc.w += v.w;
        }
        reinterpret_cast<float4*>(ws)[(size_t)blk * D4 + tid] = acc;
        return;
    }

    // ---- extract: one block per (bs, a), all 3 extracts, float4 columns ----
    const int eblk = blk - PART_BLOCKS;
    const int bs = eblk >> 3, a = eblk & 7;
    constexpr int NT = 3 * L_;                            // 24 tokens
    __shared__ int toks[NT];
    __shared__ int pos[NT];
    __shared__ float invs[3];

    if (tid < NT) {
        int e = tid >> 3, l = tid & 7;
        const int* p = (e == 0) ? pred : ((e == 1) ? arg0 : arg1);
        toks[tid] = p[(size_t)(bs * A_ + a) * L_ + l];
        pos[tid] = -1;
    }
    __syncthreads();
    if (tid < T_) {
        int id = sids[(size_t)bs * T_ + tid];
        #pragma unroll
        for (int i = 0; i < NT; ++i)
            if (toks[i] != 0 && toks[i] == id) pos[i] = tid;  // ids unique per sentence
    } else if (tid >= 128 && tid < 131) {
        int e = tid - 128, n = 0;
        #pragma unroll
        for (int l = 0; l < L_; ++l) n += (toks[e * L_ + l] != 0);
        invs[e] = 1.0f / (float)(n < 1 ? 1 : n);
    }
    __syncthreads();

    // branch-free: clamp invalid pos to row 0, weight 0 -> all 24 loads batch
    const float4* base4 = reinterpret_cast<const float4*>(emb + (size_t)bs * T_ * D_);
    float4 acc[3] = {};
    #pragma unroll
    for (int e = 0; e < 3; ++e) {
        #pragma unroll
        for (int l = 0; l < L_; ++l) {
            int p = pos[e * L_ + l];
            float w = (p >= 0) ? 1.0f : 0.0f;
            int pr = (p >= 0) ? p : 0;
            float4 v = base4[(size_t)pr * D4 + tid];
            acc[e].x += w * v.x; acc[e].y += w * v.y;
            acc[e].z += w * v.z; acc[e].w += w * v.w;
        }
    }
    #pragma unroll
    for (int e = 0; e < 3; ++e) {
        float iv = invs[e];
        float4 r = {acc[e].x * iv, acc[e].y * iv, acc[e].z * iv, acc[e].w * iv};
        reinterpret_cast<float4*>(out + MEAN_ELEMS + (size_t)e * EXT_ELEMS
                                  + (size_t)(bs * A_ + a) * D_)[tid] = r;
    }
}

// ---- dispatch 2: reduce 8 partials -> mean ----
__global__ void __launch_bounds__(256) srl_reduce(
    const float* __restrict__ ws, float* __restrict__ out)
{
    int idx = blockIdx.x * 256 + threadIdx.x;             // [0, BS*D4)
    int bs = idx / D4, d4 = idx % D4;
    const float4* w = reinterpret_cast<const float4*>(ws);
    float4 acc = {0.f, 0.f, 0.f, 0.f};
    #pragma unroll
    for (int ch = 0; ch < TSPLIT; ++ch) {
        float4 v = w[(size_t)(bs * TSPLIT + ch) * D4 + d4];
        acc.x += v.x; acc.y += v.y; acc.z += v.z; acc.w += v.w;
    }
    const float s = 1.0f / T_;
    float4 r = {acc.x * s, acc.y * s, acc.z * s, acc.w * s};
    reinterpret_cast<float4*>(out)[idx] = r;
}

// ---- fallback (ws too small): round-4 style single kernel ----
__global__ void __launch_bounds__(256) srl_fallback(
    const float* __restrict__ emb,
    const int* __restrict__ sids,
    const int* __restrict__ pred,
    const int* __restrict__ arg0,
    const int* __restrict__ arg1,
    float* __restrict__ out)
{
    const int blk = blockIdx.x;
    const int tid = threadIdx.x;
    if (blk < BS) {
        if (tid >= 192) return;
        const float4* p = reinterpret_cast<const float4*>(emb + (size_t)blk * T_ * D_) + tid;
        float4 acc = {0.f, 0.f, 0.f, 0.f};
        #pragma unroll 8
        for (int t = 0; t < T_; ++t) {
            float4 v = p[(size_t)t * D4];
            acc.x += v.x; acc.y += v.y; acc.z += v.z; acc.w += v.w;
        }
        const float s = 1.0f / T_;
        float4 r = {acc.x * s, acc.y * s, acc.z * s, acc.w * s};
        reinterpret_cast<float4*>(out)[(size_t)blk * D4 + tid] = r;
        return;
    }
    const int eblk = blk - BS;
    const int bs = eblk >> 3, a = eblk & 7;
    constexpr int NT = 3 * L_;
    __shared__ int toks[NT];
    __shared__ int pos[NT];
    __shared__ float invs[3];
    if (tid < NT) {
        int e = tid >> 3, l = tid & 7;
        const int* p = (e == 0) ? pred : ((e == 1) ? arg0 : arg1);
        toks[tid] = p[(size_t)(bs * A_ + a) * L_ + l];
        pos[tid] = -1;
    }
    __syncthreads();
    if (tid < T_) {
        int id = sids[(size_t)bs * T_ + tid];
        #pragma unroll
        for (int i = 0; i < NT; ++i)
            if (toks[i] != 0 && toks[i] == id) pos[i] = tid;
    } else if (tid >= 128 && tid < 131) {
        int e = tid - 128, n = 0;
        #pragma unroll
        for (int l = 0; l < L_; ++l) n += (toks[e * L_ + l] != 0);
        invs[e] = 1.0f / (float)(n < 1 ? 1 : n);
    }
    __syncthreads();
    if (tid >= 192) return;
    const float4* base4 = reinterpret_cast<const float4*>(emb + (size_t)bs * T_ * D_);
    float4 acc[3] = {};
    #pragma unroll
    for (int e = 0; e < 3; ++e) {
        #pragma unroll
        for (int l = 0; l < L_; ++l) {
            int p = pos[e * L_ + l];
            float w = (p >= 0) ? 1.0f : 0.0f;
            int pr = (p >= 0) ? p : 0;
            float4 v = base4[(size_t)pr * D4 + tid];
            acc[e].x += w * v.x; acc[e].y += w * v.y;
            acc[e].z += w * v.z; acc[e].w += w * v.w;
        }
    }
    #pragma unroll
    for (int e = 0; e < 3; ++e) {
        float iv = invs[e];
        float4 r = {acc[e].x * iv, acc[e].y * iv, acc[e].z * iv, acc[e].w * iv};
        reinterpret_cast<float4*>(out + MEAN_ELEMS + (size_t)e * EXT_ELEMS
                                  + (size_t)(bs * A_ + a) * D_)[tid] = r;
    }
}
} // namespace

extern "C" void kernel_launch(void* const* d_in, const int* in_sizes, int n_in,
                              void* d_out, int out_size, void* d_ws, size_t ws_size,
                              hipStream_t stream) {
    const float* emb  = (const float*)d_in[0];
    const int*   sids = (const int*)d_in[1];
    const int*   pred = (const int*)d_in[2];
    const int*   arg0 = (const int*)d_in[3];
    const int*   arg1 = (const int*)d_in[4];
    float* out = (float*)d_out;
    float* ws  = (float*)d_ws;

    if (ws_size >= WS_FLOATS * sizeof(float)) {
        srl_main<<<dim3(PART_BLOCKS + EXT_BLOCKS), dim3(NTHR), 0, stream>>>(
            emb, sids, pred, arg0, arg1, ws, out);
        srl_reduce<<<dim3(BS * D4 / 256), dim3(256), 0, stream>>>(ws, out);
    } else {
        srl_fallback<<<dim3(BS + EXT_BLOCKS), dim3(256), 0, stream>>>(
            emb, sids, pred, arg0, arg1, out);
    }
}

// Round 6
// 42.956 us; speedup vs baseline: 1.0671x; 1.0671x over previous
//
#include <hip/hip_runtime.h>

namespace {
constexpr int B_ = 32, S_ = 8, T_ = 128, D_ = 768, A_ = 8, L_ = 8;
constexpr int BS = B_ * S_;                 // 256
constexpr int MEAN_ELEMS = BS * D_;         // 196608
constexpr int EXT_ELEMS  = BS * A_ * D_;    // 1572864
constexpr int D4 = D_ / 4;                  // 192 float4 per row
constexpr int MEAN_BLOCKS = BS;             // one per (b,s)
constexpr int EXT_BLOCKS  = BS * A_;        // 2048: one per (b,s,a), all 3 extracts
constexpr int NTHR = 192;                   // one float4 column per thread

// Single dispatch. Mean blocks walk rows with a per-sentence staggered phase
// t = (t0 + k) & 127, t0 = (bs*37) & 127, so concurrent streams do NOT alias
// to the same addresses mod 4096 (row stride 3072 and sentence stride 393216
// are both 3*2^k -> without stagger all streams hit the same channel window).
__global__ void __launch_bounds__(NTHR) srl_one(
    const float* __restrict__ emb,
    const int* __restrict__ sids,
    const int* __restrict__ pred,
    const int* __restrict__ arg0,
    const int* __restrict__ arg1,
    float* __restrict__ out)
{
    const int blk = blockIdx.x;
    const int tid = threadIdx.x;

    if (blk < MEAN_BLOCKS) {
        const int bs = blk;
        const int t0 = (bs * 37) & (T_ - 1);
        const float4* p = reinterpret_cast<const float4*>(emb + (size_t)bs * T_ * D_) + tid;
        float4 acc = {0.f, 0.f, 0.f, 0.f};
        #pragma unroll 8
        for (int k = 0; k < T_; ++k) {
            int t = (t0 + k) & (T_ - 1);
            float4 v = p[(size_t)t * D4];
            acc.x += v.x; acc.y += v.y; acc.z += v.z; acc.w += v.w;
        }
        const float s = 1.0f / T_;
        float4 r = {acc.x * s, acc.y * s, acc.z * s, acc.w * s};
        reinterpret_cast<float4*>(out)[(size_t)bs * D4 + tid] = r;
        return;
    }

    // ---- extract: one block per (bs, a), all 3 extracts, float4 columns ----
    const int eblk = blk - MEAN_BLOCKS;
    const int bs = eblk >> 3, a = eblk & 7;
    constexpr int NT = 3 * L_;                            // 24 tokens
    __shared__ int toks[NT];
    __shared__ int pos[NT];
    __shared__ float invs[3];

    if (tid < NT) {
        int e = tid >> 3, l = tid & 7;
        const int* p = (e == 0) ? pred : ((e == 1) ? arg0 : arg1);
        toks[tid] = p[(size_t)(bs * A_ + a) * L_ + l];
        pos[tid] = -1;
    }
    __syncthreads();
    if (tid < T_) {
        int id = sids[(size_t)bs * T_ + tid];
        #pragma unroll
        for (int i = 0; i < NT; ++i)
            if (toks[i] != 0 && toks[i] == id) pos[i] = tid;  // ids unique per sentence
    } else if (tid >= 128 && tid < 131) {
        int e = tid - 128, n = 0;
        #pragma unroll
        for (int l = 0; l < L_; ++l) n += (toks[e * L_ + l] != 0);
        invs[e] = 1.0f / (float)(n < 1 ? 1 : n);
    }
    __syncthreads();

    // branch-free: clamp invalid pos to row 0 with weight 0 -> all 24 loads batch
    const float4* base4 = reinterpret_cast<const float4*>(emb + (size_t)bs * T_ * D_);
    float4 acc[3] = {};
    #pragma unroll
    for (int e = 0; e < 3; ++e) {
        #pragma unroll
        for (int l = 0; l < L_; ++l) {
            int p = pos[e * L_ + l];
            float w = (p >= 0) ? 1.0f : 0.0f;
            int pr = (p >= 0) ? p : 0;
            float4 v = base4[(size_t)pr * D4 + tid];
            acc[e].x += w * v.x; acc[e].y += w * v.y;
            acc[e].z += w * v.z; acc[e].w += w * v.w;
        }
    }
    #pragma unroll
    for (int e = 0; e < 3; ++e) {
        float iv = invs[e];
        float4 r = {acc[e].x * iv, acc[e].y * iv, acc[e].z * iv, acc[e].w * iv};
        reinterpret_cast<float4*>(out + MEAN_ELEMS + (size_t)e * EXT_ELEMS
                                  + (size_t)(bs * A_ + a) * D_)[tid] = r;
    }
}
} // namespace

extern "C" void kernel_launch(void* const* d_in, const int* in_sizes, int n_in,
                              void* d_out, int out_size, void* d_ws, size_t ws_size,
                              hipStream_t stream) {
    const float* emb  = (const float*)d_in[0];
    const int*   sids = (const int*)d_in[1];
    const int*   pred = (const int*)d_in[2];
    const int*   arg0 = (const int*)d_in[3];
    const int*   arg1 = (const int*)d_in[4];
    float* out = (float*)d_out;

    srl_one<<<dim3(MEAN_BLOCKS + EXT_BLOCKS), dim3(NTHR), 0, stream>>>(
        emb, sids, pred, arg0, arg1, out);
}